// Round 1
// baseline (1840.748 us; speedup 1.0000x reference)
//
#include <hip/hip_runtime.h>
#include <hip/hip_bf16.h>
#include <cstdint>

// Problem constants (fixed shapes from reference)
#define T_TOK 2048
#define HD    2880
#define ID    2880
#define NE    8
#define TOPK  4
#define ALPHA 1.702f
#define LIMIT 7.0f

typedef __attribute__((ext_vector_type(8))) short short8;   // 8 bf16 in 4 VGPRs
typedef __attribute__((ext_vector_type(4))) float floatx4;  // MFMA C/D frag

__device__ __forceinline__ ushort f32_bf16(float f) {
    union { float f; uint32_t u; } c; c.f = f;
    uint32_t u = c.u;
    uint32_t r = (u + 0x7FFFu + ((u >> 16) & 1u)) >> 16;  // RNE
    return (ushort)r;
}

// ---------------------------------------------------------------- cvt x -> bf16
__global__ __launch_bounds__(256) void cvt_x_kernel(const float* __restrict__ x,
                                                    ushort* __restrict__ xb) {
    int i = (blockIdx.x * 256 + threadIdx.x) * 4;
    float4 v = *(const float4*)(x + i);
    ushort4 o;
    o.x = f32_bf16(v.x); o.y = f32_bf16(v.y);
    o.z = f32_bf16(v.z); o.w = f32_bf16(v.w);
    *(ushort4*)(xb + i) = o;
}

// ---------------------------------------------------------------- router (fp32)
__global__ __launch_bounds__(256) void router_kernel(
    const float* __restrict__ x, const float* __restrict__ wr,
    const float* __restrict__ br, int* __restrict__ cnt,
    int* __restrict__ tok_list, float* __restrict__ wgt_list) {
    const int t = blockIdx.x, tid = threadIdx.x;
    __shared__ float sx[HD];
    __shared__ float sred[NE][4];
    for (int h = tid; h < HD; h += 256) sx[h] = x[(size_t)t * HD + h];
    __syncthreads();
    float p[NE];
#pragma unroll
    for (int e = 0; e < NE; e++) p[e] = 0.f;
    for (int h = tid; h < HD; h += 256) {
        float xv = sx[h];
#pragma unroll
        for (int e = 0; e < NE; e++) p[e] = fmaf(xv, wr[e * HD + h], p[e]);
    }
#pragma unroll
    for (int e = 0; e < NE; e++) {
#pragma unroll
        for (int off = 32; off > 0; off >>= 1) p[e] += __shfl_down(p[e], off, 64);
    }
    if ((tid & 63) == 0) {
#pragma unroll
        for (int e = 0; e < NE; e++) sred[e][tid >> 6] = p[e];
    }
    __syncthreads();
    if (tid == 0) {
        float lg[NE];
#pragma unroll
        for (int e = 0; e < NE; e++)
            lg[e] = sred[e][0] + sred[e][1] + sred[e][2] + sred[e][3] + br[e];
        int idx[TOPK]; float val[TOPK];
        unsigned used = 0;
#pragma unroll
        for (int k = 0; k < TOPK; k++) {
            int best = -1; float bv = -1e30f;
#pragma unroll
            for (int e = 0; e < NE; e++) {
                if (!((used >> e) & 1u) && lg[e] > bv) { bv = lg[e]; best = e; }
            }
            used |= 1u << best; idx[k] = best; val[k] = bv;
        }
        float m = val[0];  // descending order -> val[0] is max
        float ex[TOPK], s = 0.f;
#pragma unroll
        for (int k = 0; k < TOPK; k++) { ex[k] = __expf(val[k] - m); s += ex[k]; }
        float inv = 1.f / s;
#pragma unroll
        for (int k = 0; k < TOPK; k++) {
            int e = idx[k];
            int pos = atomicAdd(&cnt[e], 1);
            tok_list[e * T_TOK + pos] = t;
            wgt_list[e * T_TOK + pos] = ex[k] * inv;
        }
    }
}

// ---------------------------------------------------------------- prefix offsets
__global__ void offsets_kernel(const int* __restrict__ cnt, int* __restrict__ ofs) {
    if (threadIdx.x == 0 && blockIdx.x == 0) {
        int s = 0;
        for (int e = 0; e < NE; e++) { ofs[e] = s; s += cnt[e]; }
    }
}

// ---------------------------------------------------------------- stage 1: gate+up+act
// Tile: BM=128, BN=128, BK=32. 4 waves, each 64x64 per matrix (G and U).
#define LDS_S 40  // padded row stride in bf16 elems
__global__ __launch_bounds__(256, 2) void expert_gu_kernel(
    const ushort* __restrict__ xb, const float* __restrict__ wg,
    const float* __restrict__ bg, const float* __restrict__ wu,
    const float* __restrict__ bu, const int* __restrict__ cnt,
    const int* __restrict__ ofs, const int* __restrict__ tok_list,
    ushort* __restrict__ act) {
    const int e = blockIdx.z;
    const int n_e = cnt[e];
    const int mBase = blockIdx.y * 128;
    if (mBase >= n_e) return;
    const int nBase = blockIdx.x * 128;
    const int tid = threadIdx.x;

    __shared__ ushort sA[128 * LDS_S];
    __shared__ ushort sBg[128 * LDS_S];
    __shared__ ushort sBu[128 * LDS_S];
    __shared__ int sTok[128];

    if (tid < 128) {
        int slot = mBase + tid;
        sTok[tid] = tok_list[e * T_TOK + (slot < n_e ? slot : 0)];
    }
    __syncthreads();

    const int wave = tid >> 6, lane = tid & 63;
    const int wm = (wave >> 1) * 64, wn = (wave & 1) * 64;
    const int ln = lane & 15, quad = lane >> 4;

    floatx4 accG[4][4], accU[4][4];
#pragma unroll
    for (int mi = 0; mi < 4; mi++)
#pragma unroll
        for (int ni = 0; ni < 4; ni++) {
            accG[mi][ni] = (floatx4){0.f, 0.f, 0.f, 0.f};
            accU[mi][ni] = (floatx4){0.f, 0.f, 0.f, 0.f};
        }

    const float* wgE = wg + (size_t)e * ID * HD;
    const float* wuE = wu + (size_t)e * ID * HD;

    for (int k0 = 0; k0 < HD; k0 += 32) {
        // ---- A staging: 128x32 bf16, gathered rows
#pragma unroll
        for (int r = 0; r < 2; r++) {
            int lin = r * 256 + tid;
            int ar = lin >> 2, ac = lin & 3;
            uint4 v = *(const uint4*)(xb + (size_t)sTok[ar] * HD + k0 + ac * 8);
            *(uint4*)&sA[ar * LDS_S + ac * 8] = v;
        }
        // ---- B staging: two 128x32 fp32 tiles, cvt to bf16
#pragma unroll
        for (int r = 0; r < 4; r++) {
            int c = r * 256 + tid;
            int brow = c >> 3, bc = c & 7;
            int n = nBase + brow; if (n >= ID) n = ID - 1;
            float4 g4 = *(const float4*)(wgE + (size_t)n * HD + k0 + bc * 4);
            float4 u4 = *(const float4*)(wuE + (size_t)n * HD + k0 + bc * 4);
            ushort4 gg, uu;
            gg.x = f32_bf16(g4.x); gg.y = f32_bf16(g4.y);
            gg.z = f32_bf16(g4.z); gg.w = f32_bf16(g4.w);
            uu.x = f32_bf16(u4.x); uu.y = f32_bf16(u4.y);
            uu.z = f32_bf16(u4.z); uu.w = f32_bf16(u4.w);
            *(ushort4*)&sBg[brow * LDS_S + bc * 4] = gg;
            *(ushort4*)&sBu[brow * LDS_S + bc * 4] = uu;
        }
        __syncthreads();
        // ---- compute
        short8 af[4], bgf[4], buf_[4];
#pragma unroll
        for (int mi = 0; mi < 4; mi++)
            af[mi] = *(const short8*)&sA[(wm + mi * 16 + ln) * LDS_S + quad * 8];
#pragma unroll
        for (int ni = 0; ni < 4; ni++) {
            bgf[ni] = *(const short8*)&sBg[(wn + ni * 16 + ln) * LDS_S + quad * 8];
            buf_[ni] = *(const short8*)&sBu[(wn + ni * 16 + ln) * LDS_S + quad * 8];
        }
#pragma unroll
        for (int mi = 0; mi < 4; mi++)
#pragma unroll
            for (int ni = 0; ni < 4; ni++) {
                accG[mi][ni] = __builtin_amdgcn_mfma_f32_16x16x32_bf16(
                    af[mi], bgf[ni], accG[mi][ni], 0, 0, 0);
                accU[mi][ni] = __builtin_amdgcn_mfma_f32_16x16x32_bf16(
                    af[mi], buf_[ni], accU[mi][ni], 0, 0, 0);
            }
        __syncthreads();
    }

    // ---- epilogue: bias + clamp + swiglu, store bf16 act
    const int row0 = ofs[e] + mBase;
#pragma unroll
    for (int mi = 0; mi < 4; mi++) {
#pragma unroll
        for (int r = 0; r < 4; r++) {
            int ml = wm + mi * 16 + quad * 4 + r;
            if (mBase + ml >= n_e) continue;
#pragma unroll
            for (int ni = 0; ni < 4; ni++) {
                int n = nBase + wn + ni * 16 + ln;
                if (n < ID) {
                    float g = accG[mi][ni][r] + bg[e * ID + n];
                    float u = accU[mi][ni][r] + bu[e * ID + n];
                    g = fminf(g, LIMIT);
                    u = fminf(fmaxf(u, -LIMIT), LIMIT);
                    float sg = 1.0f / (1.0f + __expf(-ALPHA * g));
                    float a = (u + 1.0f) * (g * sg);
                    act[(size_t)(row0 + ml) * ID + n] = f32_bf16(a);
                }
            }
        }
    }
}

// ---------------------------------------------------------------- stage 2: down proj
__global__ __launch_bounds__(256, 2) void expert_down_kernel(
    const ushort* __restrict__ act, const float* __restrict__ w2,
    const float* __restrict__ b2, const int* __restrict__ cnt,
    const int* __restrict__ ofs, const int* __restrict__ tok_list,
    const float* __restrict__ wgt_list, float* __restrict__ out) {
    const int e = blockIdx.z;
    const int n_e = cnt[e];
    const int mBase = blockIdx.y * 128;
    if (mBase >= n_e) return;
    const int nBase = blockIdx.x * 128;
    const int tid = threadIdx.x;

    __shared__ ushort sA[128 * LDS_S];
    __shared__ ushort sB[128 * LDS_S];
    __shared__ int sTok[128];
    __shared__ float sWgt[128];

    if (tid < 128) {
        int slot = mBase + tid;
        int cs = (slot < n_e) ? slot : 0;
        sTok[tid] = tok_list[e * T_TOK + cs];
        sWgt[tid] = wgt_list[e * T_TOK + cs];
    }
    __syncthreads();

    const int wave = tid >> 6, lane = tid & 63;
    const int wm = (wave >> 1) * 64, wn = (wave & 1) * 64;
    const int ln = lane & 15, quad = lane >> 4;
    const int row0 = ofs[e] + mBase;

    floatx4 acc[4][4];
#pragma unroll
    for (int mi = 0; mi < 4; mi++)
#pragma unroll
        for (int ni = 0; ni < 4; ni++) acc[mi][ni] = (floatx4){0.f, 0.f, 0.f, 0.f};

    const float* w2E = w2 + (size_t)e * HD * ID;

    for (int k0 = 0; k0 < ID; k0 += 32) {
#pragma unroll
        for (int r = 0; r < 2; r++) {
            int lin = r * 256 + tid;
            int ar = lin >> 2, ac = lin & 3;
            int rr = (mBase + ar < n_e) ? ar : 0;  // stay inside packed act
            uint4 v = *(const uint4*)(act + (size_t)(row0 + rr) * ID + k0 + ac * 8);
            *(uint4*)&sA[ar * LDS_S + ac * 8] = v;
        }
#pragma unroll
        for (int r = 0; r < 4; r++) {
            int c = r * 256 + tid;
            int brow = c >> 3, bc = c & 7;
            int n = nBase + brow; if (n >= HD) n = HD - 1;
            float4 b4 = *(const float4*)(w2E + (size_t)n * ID + k0 + bc * 4);
            ushort4 bb;
            bb.x = f32_bf16(b4.x); bb.y = f32_bf16(b4.y);
            bb.z = f32_bf16(b4.z); bb.w = f32_bf16(b4.w);
            *(ushort4*)&sB[brow * LDS_S + bc * 4] = bb;
        }
        __syncthreads();
        short8 af[4], bf[4];
#pragma unroll
        for (int mi = 0; mi < 4; mi++)
            af[mi] = *(const short8*)&sA[(wm + mi * 16 + ln) * LDS_S + quad * 8];
#pragma unroll
        for (int ni = 0; ni < 4; ni++)
            bf[ni] = *(const short8*)&sB[(wn + ni * 16 + ln) * LDS_S + quad * 8];
#pragma unroll
        for (int mi = 0; mi < 4; mi++)
#pragma unroll
            for (int ni = 0; ni < 4; ni++)
                acc[mi][ni] = __builtin_amdgcn_mfma_f32_16x16x32_bf16(
                    af[mi], bf[ni], acc[mi][ni], 0, 0, 0);
        __syncthreads();
    }

#pragma unroll
    for (int mi = 0; mi < 4; mi++) {
#pragma unroll
        for (int r = 0; r < 4; r++) {
            int ml = wm + mi * 16 + quad * 4 + r;
            if (mBase + ml >= n_e) continue;
            int token = sTok[ml];
            float wgt = sWgt[ml];
#pragma unroll
            for (int ni = 0; ni < 4; ni++) {
                int n = nBase + wn + ni * 16 + ln;
                if (n < HD) {
                    float v = (acc[mi][ni][r] + b2[e * HD + n]) * wgt;
                    atomicAdd(&out[(size_t)token * HD + n], v);
                }
            }
        }
    }
}

// ---------------------------------------------------------------- launch
extern "C" void kernel_launch(void* const* d_in, const int* in_sizes, int n_in,
                              void* d_out, int out_size, void* d_ws, size_t ws_size,
                              hipStream_t stream) {
    const float* x  = (const float*)d_in[0];
    const float* wr = (const float*)d_in[1];
    const float* br = (const float*)d_in[2];
    const float* wg = (const float*)d_in[3];
    const float* bg = (const float*)d_in[4];
    const float* wu = (const float*)d_in[5];
    const float* bu = (const float*)d_in[6];
    const float* w2 = (const float*)d_in[7];
    const float* b2 = (const float*)d_in[8];
    float* out = (float*)d_out;

    // workspace layout (~59.1 MB)
    char* ws = (char*)d_ws;
    int*    cnt      = (int*)ws;                        // 32 B used
    int*    ofs      = (int*)(ws + 256);
    int*    tok_list = (int*)(ws + 512);                // E*T*4   = 65536
    float*  wgt_list = (float*)(ws + 512 + 65536);      // E*T*4   = 65536
    ushort* xb       = (ushort*)(ws + 512 + 131072);    // T*H*2   = 11796480
    ushort* act      = (ushort*)(ws + 512 + 131072 + 11796480);  // 8192*I*2 = 47185920

    hipMemsetAsync(out, 0, (size_t)T_TOK * HD * sizeof(float), stream);
    hipMemsetAsync(cnt, 0, NE * sizeof(int), stream);

    cvt_x_kernel<<<(T_TOK * HD) / 4 / 256, 256, 0, stream>>>(x, xb);
    router_kernel<<<T_TOK, 256, 0, stream>>>(x, wr, br, cnt, tok_list, wgt_list);
    offsets_kernel<<<1, 64, 0, stream>>>(cnt, ofs);

    dim3 g1((ID + 127) / 128, T_TOK / 128, NE);
    expert_gu_kernel<<<g1, 256, 0, stream>>>(xb, wg, bg, wu, bu, cnt, ofs, tok_list, act);

    dim3 g2((HD + 127) / 128, T_TOK / 128, NE);
    expert_down_kernel<<<g2, 256, 0, stream>>>(act, w2, b2, cnt, ofs, tok_list, wgt_list, out);
}